// Round 8
// baseline (206.792 us; speedup 1.0000x reference)
//
#include <hip/hip_runtime.h>
#include <hip/hip_fp16.h>

#define N_NODES 65536
#define N_EDGES 1048576
#define F_IN    16
#define H       64
#define N_GRAPHS 32
#define NPG     2048
#define OUT_F   12
#define KPG     (NPG * H)   // 131072 per-graph K for FC
#define CAP     4864        // padded per-bucket capacity: mean 4096, sigma 64, +12 sigma
#define NPB     16          // nodes per block in agg kernels

// ================================================================ CSR build
// Edges pack into uint32: src (16b) | dst (16b) << 16.
// Bucket = dst>>8 (256 buckets of 256 nodes), FIXED padded regions of CAP edges.

// 1 tiny block: init cursors to padded bucket bases; bias-init out
__global__ __launch_bounds__(256) void init_kernel(int* __restrict__ gCursor,
                                                   const float* __restrict__ bfc,
                                                   float* __restrict__ out) {
    int t = threadIdx.x;
    gCursor[t] = t * CAP;
    for (int i = t; i < N_GRAPHS * OUT_F; i += 256) out[i] = bfc[i % OUT_F];
}

// 256 blocks x 4096 edges: LDS-staged bin by dst>>8, coalesced flush into bucket regions
__global__ __launch_bounds__(256) void binA_kernel(const int* __restrict__ src,
                                                   const int* __restrict__ dst,
                                                   int* __restrict__ gCursor,
                                                   unsigned int* __restrict__ binned) {
    __shared__ int hist[256];
    __shared__ int sc[256];
    __shared__ int bnd[257];
    __shared__ int lcur[256];
    __shared__ int blkBase[256];
    __shared__ unsigned int staged[4096];
    int t = threadIdx.x;
    hist[t] = 0; lcur[t] = 0;
    __syncthreads();
    int e0 = blockIdx.x * 4096;
    unsigned int rec[16];
#pragma unroll
    for (int i = 0; i < 16; i++) {
        int e = e0 + i * 256 + t;
        unsigned int s = (unsigned int)src[e];
        unsigned int d = (unsigned int)dst[e];
        rec[i] = s | (d << 16);
        atomicAdd(&hist[d >> 8], 1);
    }
    __syncthreads();
    int cnt = hist[t];
    if (cnt) blkBase[t] = atomicAdd(&gCursor[t], cnt);
    sc[t] = cnt;
    __syncthreads();
    for (int off = 1; off < 256; off <<= 1) {
        int v = (t >= off) ? sc[t - off] : 0;
        __syncthreads();
        sc[t] += v;
        __syncthreads();
    }
    bnd[t] = sc[t] - cnt;
    if (t == 255) bnd[256] = 4096;
    __syncthreads();
#pragma unroll
    for (int i = 0; i < 16; i++) {
        int b = rec[i] >> 24;
        int p = bnd[b] + atomicAdd(&lcur[b], 1);
        staged[p] = rec[i];
    }
    __syncthreads();
    for (int i = t; i < 4096; i += 256) {
        int lo = 0;
#pragma unroll
        for (int s = 128; s > 0; s >>= 1)
            if (bnd[lo + s] <= i) lo += s;
        binned[blkBase[lo] + (i - bnd[lo])] = staged[i];
    }
}

// block per bucket: counting sort -> nbr (ushort), rowinfo{start,cnt}; fused g1h write
__global__ __launch_bounds__(256) void binB_g1_kernel(const unsigned int* __restrict__ binned,
                                                      const int* __restrict__ gCursor,
                                                      const float* __restrict__ x,
                                                      int2* __restrict__ rowinfo,
                                                      unsigned short* __restrict__ nbr,
                                                      __half2* __restrict__ g1h) {
    __shared__ int hist[256];
    __shared__ int sc[256];
    __shared__ int off[256];
    __shared__ int cur[256];
    __shared__ unsigned short outS[8192];
    int b = blockIdx.x, t = threadIdx.x;
    int base = b * CAP;
    int cnt  = gCursor[b] - base;   // actual edges in this bucket after binA
    hist[t] = 0; cur[t] = 0;
    __syncthreads();
    for (int i = t; i < cnt; i += 256) {
        unsigned int r = binned[base + i];
        atomicAdd(&hist[(r >> 16) & 255], 1);
    }
    __syncthreads();
    int c = hist[t];
    sc[t] = c;
    __syncthreads();
    for (int o = 1; o < 256; o <<= 1) {
        int v = (t >= o) ? sc[t - o] : 0;
        __syncthreads();
        sc[t] += v;
        __syncthreads();
    }
    off[t] = sc[t] - c;
    int nd = (b << 8) + t;
    float dv = rsqrtf((float)(c + 1));
    rowinfo[nd] = make_int2(base + sc[t] - c, c);
    {
        const float4* xr = (const float4*)(x + (size_t)nd * F_IN);
        float4 x0 = xr[0], x1 = xr[1], x2 = xr[2], x3 = xr[3];
        __half2* gr = g1h + nd * 8;
        gr[0] = __floats2half2_rn(x0.x * dv, x0.y * dv);
        gr[1] = __floats2half2_rn(x0.z * dv, x0.w * dv);
        gr[2] = __floats2half2_rn(x1.x * dv, x1.y * dv);
        gr[3] = __floats2half2_rn(x1.z * dv, x1.w * dv);
        gr[4] = __floats2half2_rn(x2.x * dv, x2.y * dv);
        gr[5] = __floats2half2_rn(x2.z * dv, x2.w * dv);
        gr[6] = __floats2half2_rn(x3.x * dv, x3.y * dv);
        gr[7] = __floats2half2_rn(x3.z * dv, x3.w * dv);
    }
    __syncthreads();
    for (int i = t; i < cnt; i += 256) {
        unsigned int r = binned[base + i];
        int n = (r >> 16) & 255;
        int p = off[n] + atomicAdd(&cur[n], 1);
        outS[p] = (unsigned short)(r & 0xFFFF);
    }
    __syncthreads();
    for (int i = t; i < cnt; i += 256) nbr[base + i] = outS[i];
}

// ---------------------------------------------------------------- unpack helpers
__device__ __forceinline__ void add8(float* acc, float4 q) {
    union { float4 f; __half2 h[4]; } u; u.f = q;
#pragma unroll
    for (int c = 0; c < 4; c++) {
        float2 p = __half22float2(u.h[c]);
        acc[2 * c]     += p.x;
        acc[2 * c + 1] += p.y;
    }
}
__device__ __forceinline__ void add4(float* acc, float2 q) {
    union { float2 f; __half2 h[2]; } u; u.f = q;
    float2 p0 = __half22float2(u.h[0]);
    float2 p1 = __half22float2(u.h[1]);
    acc[0] += p0.x; acc[1] += p0.y; acc[2] += p1.x; acc[3] += p1.y;
}

// ================================================================ layer 1 (fused agg + gemm)
// Wave-per-node. Upfront-batched gather: the 2 loads covering edges 0..31
// (>99.9% of rows) issue back-to-back BEFORE any unpack/add, doubling
// in-flight bytes vs the load-add-load-add tail loop.
__global__ __launch_bounds__(256) void agg1_gemm1_kernel(const __half2* __restrict__ g1h,
                                                         const int2* __restrict__ rowinfo,
                                                         const unsigned short* __restrict__ nbr,
                                                         const float* __restrict__ W1,
                                                         const float* __restrict__ b1,
                                                         __half* __restrict__ g2h) {
    const float2* g1v = (const float2*)g1h;   // row = 4 float2
    __shared__ float Ws[F_IN * H];
    __shared__ float bs[H];
    int t = threadIdx.x;
    for (int i = t; i < F_IN * H; i += 256) Ws[i] = W1[i];
    if (t < H) bs[t] = b1[t];
    __syncthreads();
    int lane = t & 63;
    int w    = t >> 6;
    int f4   = lane & 3;
    int sub  = lane >> 2;          // 16 edge-slots per batch
    int v    = blockIdx.x * NPB + w;
    int2 ri  = rowinfo[v];
    int nb   = (int)nbr[ri.x + lane];
#pragma unroll 1
    for (int it = 0; it < NPB / 4; ++it) {
        int vc = v;
        int r0 = ri.x, er = ri.y;
        int nbc = nb;
        float2 sq = g1v[(vc << 2) + f4];      // self row, early
        // upfront: edges 0..31 via 2 independent loads
        int s0 = sub, s1 = 16 + sub;
        int u0 = __shfl(nbc, s0 < er ? s0 : 0, 64);
        int u1 = __shfl(nbc, s1 < er ? s1 : 0, 64);
        float2 q0 = g1v[(u0 << 2) + f4];
        float2 q1 = g1v[(u1 << 2) + f4];
        if (it < NPB / 4 - 1) ri = rowinfo[vc + 4];   // prefetch next rowinfo
        float acc[4] = {0.f, 0.f, 0.f, 0.f};
        if (s0 < er) add4(acc, q0);
        if (s1 < er) add4(acc, q1);
        // tail: er > 32 (rare)
        int j = 32;
        for (; j + 32 <= er; j += 32) {
            int a0 = __shfl(nbc, j + sub, 64);
            int a1 = __shfl(nbc, j + 16 + sub, 64);
            float2 t0 = g1v[(a0 << 2) + f4];
            float2 t1 = g1v[(a1 << 2) + f4];
            add4(acc, t0);
            add4(acc, t1);
        }
        for (; j < er && j < 64; j += 16) {
            int idx = j + sub;
            int u = __shfl(nbc, idx < er ? idx : 0, 64);
            float2 q = g1v[(u << 2) + f4];
            if (idx < er) add4(acc, q);
        }
        for (int base = 64; base < er; base += 64) {   // essentially never (deg>64)
            int nbx = (int)nbr[r0 + base + lane];
            for (int jj = 0; jj < 64 && base + jj < er; jj += 16) {
                int idx = jj + sub;
                int u = __shfl(nbx, (base + idx) < er ? idx : 0, 64);
                float2 q = g1v[(u << 2) + f4];
                if (base + idx < er) add4(acc, q);
            }
        }
        if (it < NPB / 4 - 1) nb = (int)nbr[ri.x + lane];  // prefetch next nbr chunk
#pragma unroll
        for (int i = 0; i < 4; i++) {
            acc[i] += __shfl_xor(acc[i], 4, 64);
            acc[i] += __shfl_xor(acc[i], 8, 64);
            acc[i] += __shfl_xor(acc[i], 16, 64);
            acc[i] += __shfl_xor(acc[i], 32, 64);
        }
        add4(acc, sq);
        float dv = rsqrtf((float)(er + 1));
#pragma unroll
        for (int i = 0; i < 4; i++) acc[i] *= dv;
        // in-wave GEMM: feature k lives at lane (k>>2), component (k&3)
        float s = bs[lane];
#pragma unroll
        for (int k = 0; k < F_IN; ++k) {
            float bk = __shfl(acc[k & 3], k >> 2, 64);
            s += bk * Ws[k * H + lane];
        }
        g2h[(vc << 6) + lane] = __float2half(dv * tanhf(s));
        v += 4;
    }
}

// ================================================================ layer 2 aggregation (PURE gather)
// Wave-per-node. Upfront-batched: 4 independent float4 loads covering edges
// 0..31 issue before any unpack -- 2x the in-flight bytes of the old loop.
__global__ __launch_bounds__(256) void agg2_kernel(const __half2* __restrict__ g2h,
                                                   const int2* __restrict__ rowinfo,
                                                   const unsigned short* __restrict__ nbr,
                                                   float* __restrict__ a2) {
    const float4* g2v = (const float4*)g2h;   // row = 8 float4
    int t    = threadIdx.x;
    int lane = t & 63;
    int w    = t >> 6;
    int f8   = lane & 7;
    int sub  = lane >> 3;          // 8 edge-slots per batch
    int v    = blockIdx.x * NPB + w;
    int2 ri  = rowinfo[v];
    int nb   = (int)nbr[ri.x + lane];
#pragma unroll 1
    for (int it = 0; it < NPB / 4; ++it) {
        int vc = v;
        int r0 = ri.x, er = ri.y;
        int nbc = nb;
        float4 sq = g2v[(vc << 3) + f8];      // self row, early
        // upfront: edges 0..31 via 4 independent loads
        int s0 = sub, s1 = 8 + sub, s2 = 16 + sub, s3 = 24 + sub;
        int u0 = __shfl(nbc, s0 < er ? s0 : 0, 64);
        int u1 = __shfl(nbc, s1 < er ? s1 : 0, 64);
        int u2 = __shfl(nbc, s2 < er ? s2 : 0, 64);
        int u3 = __shfl(nbc, s3 < er ? s3 : 0, 64);
        float4 q0 = g2v[(u0 << 3) + f8];
        float4 q1 = g2v[(u1 << 3) + f8];
        float4 q2 = g2v[(u2 << 3) + f8];
        float4 q3 = g2v[(u3 << 3) + f8];
        if (it < NPB / 4 - 1) ri = rowinfo[vc + 4];   // prefetch next rowinfo
        float acc[8] = {0.f, 0.f, 0.f, 0.f, 0.f, 0.f, 0.f, 0.f};
        if (s0 < er) add8(acc, q0);
        if (s1 < er) add8(acc, q1);
        if (s2 < er) add8(acc, q2);
        if (s3 < er) add8(acc, q3);
        // tail: er > 32 (rare)
        int j = 32;
        for (; j + 16 <= er && j < 64; j += 16) {
            int a0 = __shfl(nbc, j + sub, 64);
            int a1 = __shfl(nbc, j + 8 + sub, 64);
            float4 t0 = g2v[(a0 << 3) + f8];
            float4 t1 = g2v[(a1 << 3) + f8];
            add8(acc, t0);
            add8(acc, t1);
        }
        for (; j < er && j < 64; j += 8) {
            int idx = j + sub;
            int u = __shfl(nbc, idx < er ? idx : 0, 64);
            float4 q = g2v[(u << 3) + f8];
            if (idx < er) add8(acc, q);
        }
        for (int base = 64; base < er; base += 64) {   // essentially never (deg>64)
            int nbx = (int)nbr[r0 + base + lane];
            for (int jj = 0; jj < 64 && base + jj < er; jj += 8) {
                int idx = jj + sub;
                int u = __shfl(nbx, (base + idx) < er ? idx : 0, 64);
                float4 q = g2v[(u << 3) + f8];
                if (base + idx < er) add8(acc, q);
            }
        }
        if (it < NPB / 4 - 1) nb = (int)nbr[ri.x + lane];  // prefetch next nbr chunk
#pragma unroll
        for (int i = 0; i < 8; i++) {
            acc[i] += __shfl_xor(acc[i], 8, 64);
            acc[i] += __shfl_xor(acc[i], 16, 64);
            acc[i] += __shfl_xor(acc[i], 32, 64);
        }
        add8(acc, sq);
        float dv = rsqrtf((float)(er + 1));
#pragma unroll
        for (int i = 0; i < 8; i++) acc[i] *= dv;
        if (sub == 0) {
            float4* dp = (float4*)(a2 + ((size_t)vc << 6) + (f8 << 3));
            dp[0] = make_float4(acc[0], acc[1], acc[2], acc[3]);
            dp[1] = make_float4(acc[4], acc[5], acc[6], acc[7]);
        }
        v += 4;
    }
}

// ================================================================ gemm2 + fused FC head (graph-blocked)
// Block = 2 node-POSITIONS x all 32 graphs (64 nodes). The per-lane Wfc slice
// (2 x 48B) sits in registers and each Wfc element is read from memory exactly
// ONCE chip-wide (6.3 MB total, vs 201 MB with position-major blocking).
// GEMM: same LDS blocking as before (Ws column reads reused across 16 nodes,
// wave-uniform b128 a-reads broadcast). Wave w covers graphs w*8..w*8+7.
__global__ __launch_bounds__(256) void gemm2_fc_kernel(const float* __restrict__ a2,
                                                       const float* __restrict__ W2,
                                                       const float* __restrict__ b2,
                                                       const float* __restrict__ Wfc,
                                                       float* __restrict__ out) {
    __shared__ float Ws[H * H];     // 16 KB, [k][o]
    __shared__ float As[64 * H];    // 16 KB, [node n = g*2+q][k]
    __shared__ float bs[H];
    __shared__ float red[N_GRAPHS * OUT_F];   // 1.5 KB
    int t = threadIdx.x;
    for (int i = t; i < H * H; i += 256) Ws[i] = W2[i];
    if (t < H) bs[t] = b2[t];
    int p0 = blockIdx.x << 1;       // two positions p0, p0+1
    {   // stage 64 rows (n = g*2+q -> global node g*2048 + p0 + q)
        const float4* a4 = (const float4*)a2;
        float4* asp = (float4*)As;
#pragma unroll
        for (int i = 0; i < 4; i++) {
            int i4 = i * 256 + t;
            int n = i4 >> 4, c = i4 & 15;
            int g = n >> 1, q = n & 1;
            asp[i4] = a4[(size_t)((g << 11) + p0 + q) * 16 + c];
        }
    }
    int lane = t & 63, w = t >> 6;
    // per-lane Wfc slices for the two positions (read once chip-wide)
    float4 wf0a, wf0b, wf0c, wf1a, wf1b, wf1c;
    {
        const float4* wr0 = (const float4*)(Wfc + (size_t)(p0 * H + lane) * OUT_F);
        const float4* wr1 = (const float4*)(Wfc + (size_t)((p0 + 1) * H + lane) * OUT_F);
        wf0a = wr0[0]; wf0b = wr0[1]; wf0c = wr0[2];
        wf1a = wr1[0]; wf1b = wr1[1]; wf1c = wr1[2];
    }
    __syncthreads();
    float acc[16];
#pragma unroll
    for (int j = 0; j < 16; j++) acc[j] = bs[lane];
    const float* asBase = As + ((w << 4) * H);
#pragma unroll 2
    for (int kc = 0; kc < H / 4; ++kc) {
        int k0 = kc << 2;
        float w0 = Ws[(k0 + 0) * H + lane];
        float w1 = Ws[(k0 + 1) * H + lane];
        float w2 = Ws[(k0 + 2) * H + lane];
        float w3 = Ws[(k0 + 3) * H + lane];
#pragma unroll
        for (int j = 0; j < 16; ++j) {
            float4 aq = *(const float4*)(asBase + j * H + k0);   // wave-uniform -> broadcast
            acc[j] += aq.x * w0 + aq.y * w1 + aq.z * w2 + aq.w * w3;
        }
    }
    // FC: graphs w*8+gg, two nodes (q=0,1) each
#pragma unroll
    for (int gg = 0; gg < 8; ++gg) {
        float h0 = tanhf(acc[2 * gg]);
        float h1 = tanhf(acc[2 * gg + 1]);
        float pa[OUT_F];
        pa[0]  = h0 * wf0a.x + h1 * wf1a.x;  pa[1]  = h0 * wf0a.y + h1 * wf1a.y;
        pa[2]  = h0 * wf0a.z + h1 * wf1a.z;  pa[3]  = h0 * wf0a.w + h1 * wf1a.w;
        pa[4]  = h0 * wf0b.x + h1 * wf1b.x;  pa[5]  = h0 * wf0b.y + h1 * wf1b.y;
        pa[6]  = h0 * wf0b.z + h1 * wf1b.z;  pa[7]  = h0 * wf0b.w + h1 * wf1b.w;
        pa[8]  = h0 * wf0c.x + h1 * wf1c.x;  pa[9]  = h0 * wf0c.y + h1 * wf1c.y;
        pa[10] = h0 * wf0c.z + h1 * wf1c.z;  pa[11] = h0 * wf0c.w + h1 * wf1c.w;
#pragma unroll
        for (int j = 0; j < OUT_F; j++) {
            float vv = pa[j];
            vv += __shfl_xor(vv, 1, 64);  vv += __shfl_xor(vv, 2, 64);
            vv += __shfl_xor(vv, 4, 64);  vv += __shfl_xor(vv, 8, 64);
            vv += __shfl_xor(vv, 16, 64); vv += __shfl_xor(vv, 32, 64);
            pa[j] = vv;
        }
        if (lane == 0) {
#pragma unroll
            for (int j = 0; j < OUT_F; j++) red[(w * 8 + gg) * OUT_F + j] = pa[j];
        }
    }
    __syncthreads();
    for (int i = t; i < N_GRAPHS * OUT_F; i += 256)
        atomicAdd(&out[i], red[i]);
}

// ================================================================ launcher
extern "C" void kernel_launch(void* const* d_in, const int* in_sizes, int n_in,
                              void* d_out, int out_size, void* d_ws, size_t ws_size,
                              hipStream_t stream) {
    const float* x    = (const float*)d_in[0];
    const int*   edge = (const int*)d_in[1];
    const int*   src  = edge;
    const int*   dst  = edge + N_EDGES;
    const float* W1  = (const float*)d_in[3];
    const float* b1  = (const float*)d_in[4];
    const float* W2  = (const float*)d_in[5];
    const float* b2  = (const float*)d_in[6];
    const float* Wfc = (const float*)d_in[7];
    const float* bfc = (const float*)d_in[8];
    float* out = (float*)d_out;

    char* p = (char*)d_ws;
    auto alloc = [&](size_t n) { char* r = p; p += (n + 255) & ~(size_t)255; return r; };
    int*   gCursor    = (int*)alloc(256 * 4);
    int2*  rowinfo    = (int2*)alloc((size_t)N_NODES * 8);
    unsigned short* nbr = (unsigned short*)alloc((size_t)256 * CAP * 2 + 256); // pad: prefetch reads up to +63
    __half* g1h       = (__half*)alloc((size_t)N_NODES * F_IN * 2);
    __half* g2h       = (__half*)alloc((size_t)N_NODES * H * 2);
    float* a2         = (float*)alloc((size_t)N_NODES * H * 4);
    unsigned int* binned = (unsigned int*)alloc((size_t)256 * CAP * 4);

    init_kernel<<<1, 256, 0, stream>>>(gCursor, bfc, out);
    binA_kernel<<<256, 256, 0, stream>>>(src, dst, gCursor, binned);
    binB_g1_kernel<<<256, 256, 0, stream>>>(binned, gCursor, x, rowinfo, nbr,
                                            (__half2*)g1h);
    agg1_gemm1_kernel<<<N_NODES / NPB, 256, 0, stream>>>((const __half2*)g1h, rowinfo, nbr,
                                                         W1, b1, g2h);
    agg2_kernel<<<N_NODES / NPB, 256, 0, stream>>>((const __half2*)g2h, rowinfo, nbr, a2);
    gemm2_fc_kernel<<<NPG / 2, 256, 0, stream>>>(a2, W2, b2, Wfc, out);
}

// Round 9
// 188.525 us; speedup vs baseline: 1.0969x; 1.0969x over previous
//
#include <hip/hip_runtime.h>
#include <hip/hip_fp16.h>

#define N_NODES 65536
#define N_EDGES 1048576
#define F_IN    16
#define H       64
#define N_GRAPHS 32
#define NPG     2048
#define OUT_F   12
#define KPG     (NPG * H)   // 131072 per-graph K for FC
#define CAP     4864        // padded per-bucket capacity: mean 4096, sigma 64, +12 sigma
#define NPB     16          // nodes per block in agg kernels

// ================================================================ CSR build
// Edges pack into uint32: src (16b) | dst (16b) << 16.
// Bucket = dst>>8 (256 buckets of 256 nodes), FIXED padded regions of CAP edges.

// 1 tiny block: init cursors to padded bucket bases; bias-init out
__global__ __launch_bounds__(256) void init_kernel(int* __restrict__ gCursor,
                                                   const float* __restrict__ bfc,
                                                   float* __restrict__ out) {
    int t = threadIdx.x;
    gCursor[t] = t * CAP;
    for (int i = t; i < N_GRAPHS * OUT_F; i += 256) out[i] = bfc[i % OUT_F];
}

// 256 blocks x 4096 edges: LDS-staged bin by dst>>8, coalesced flush into bucket regions
__global__ __launch_bounds__(256) void binA_kernel(const int* __restrict__ src,
                                                   const int* __restrict__ dst,
                                                   int* __restrict__ gCursor,
                                                   unsigned int* __restrict__ binned) {
    __shared__ int hist[256];
    __shared__ int sc[256];
    __shared__ int bnd[256];
    __shared__ int lcur[256];
    __shared__ int blkBase[256];
    __shared__ unsigned int staged[4096];
    int t = threadIdx.x;
    hist[t] = 0; lcur[t] = 0;
    __syncthreads();
    int e0 = blockIdx.x * 4096;
    unsigned int rec[16];
#pragma unroll
    for (int i = 0; i < 16; i++) {
        int e = e0 + i * 256 + t;
        unsigned int s = (unsigned int)src[e];
        unsigned int d = (unsigned int)dst[e];
        rec[i] = s | (d << 16);
        atomicAdd(&hist[d >> 8], 1);
    }
    __syncthreads();
    int cnt = hist[t];
    if (cnt) blkBase[t] = atomicAdd(&gCursor[t], cnt);
    sc[t] = cnt;
    __syncthreads();
    for (int off = 1; off < 256; off <<= 1) {
        int v = (t >= off) ? sc[t - off] : 0;
        __syncthreads();
        sc[t] += v;
        __syncthreads();
    }
    bnd[t] = sc[t] - cnt;
    __syncthreads();
#pragma unroll
    for (int i = 0; i < 16; i++) {
        int b = rec[i] >> 24;
        int p = bnd[b] + atomicAdd(&lcur[b], 1);
        staged[p] = rec[i];
    }
    __syncthreads();
    // flush: bucket of staged[i] is its own top byte -- direct lookup, no search
    for (int i = t; i < 4096; i += 256) {
        unsigned int r = staged[i];
        int b = r >> 24;
        binned[blkBase[b] + (i - bnd[b])] = r;
    }
}

// block per bucket: counting sort -> nbr (ushort), rowinfo{start,cnt}; fused g1h write
__global__ __launch_bounds__(256) void binB_g1_kernel(const unsigned int* __restrict__ binned,
                                                      const int* __restrict__ gCursor,
                                                      const float* __restrict__ x,
                                                      int2* __restrict__ rowinfo,
                                                      unsigned short* __restrict__ nbr,
                                                      __half2* __restrict__ g1h) {
    __shared__ int hist[256];
    __shared__ int sc[256];
    __shared__ int off[256];
    __shared__ int cur[256];
    __shared__ unsigned short outS[8192];
    int b = blockIdx.x, t = threadIdx.x;
    int base = b * CAP;
    int cnt  = gCursor[b] - base;   // actual edges in this bucket after binA
    hist[t] = 0; cur[t] = 0;
    __syncthreads();
    for (int i = t; i < cnt; i += 256) {
        unsigned int r = binned[base + i];
        atomicAdd(&hist[(r >> 16) & 255], 1);
    }
    __syncthreads();
    int c = hist[t];
    sc[t] = c;
    __syncthreads();
    for (int o = 1; o < 256; o <<= 1) {
        int v = (t >= o) ? sc[t - o] : 0;
        __syncthreads();
        sc[t] += v;
        __syncthreads();
    }
    off[t] = sc[t] - c;
    int nd = (b << 8) + t;
    float dv = rsqrtf((float)(c + 1));
    rowinfo[nd] = make_int2(base + sc[t] - c, c);
    {
        const float4* xr = (const float4*)(x + (size_t)nd * F_IN);
        float4 x0 = xr[0], x1 = xr[1], x2 = xr[2], x3 = xr[3];
        __half2* gr = g1h + nd * 8;
        gr[0] = __floats2half2_rn(x0.x * dv, x0.y * dv);
        gr[1] = __floats2half2_rn(x0.z * dv, x0.w * dv);
        gr[2] = __floats2half2_rn(x1.x * dv, x1.y * dv);
        gr[3] = __floats2half2_rn(x1.z * dv, x1.w * dv);
        gr[4] = __floats2half2_rn(x2.x * dv, x2.y * dv);
        gr[5] = __floats2half2_rn(x2.z * dv, x2.w * dv);
        gr[6] = __floats2half2_rn(x3.x * dv, x3.y * dv);
        gr[7] = __floats2half2_rn(x3.z * dv, x3.w * dv);
    }
    __syncthreads();
    for (int i = t; i < cnt; i += 256) {
        unsigned int r = binned[base + i];
        int n = (r >> 16) & 255;
        int p = off[n] + atomicAdd(&cur[n], 1);
        outS[p] = (unsigned short)(r & 0xFFFF);
    }
    __syncthreads();
    for (int i = t; i < cnt; i += 256) nbr[base + i] = outS[i];
}

// ---------------------------------------------------------------- unpack helpers
__device__ __forceinline__ void add8(float* acc, float4 q) {
    union { float4 f; __half2 h[4]; } u; u.f = q;
#pragma unroll
    for (int c = 0; c < 4; c++) {
        float2 p = __half22float2(u.h[c]);
        acc[2 * c]     += p.x;
        acc[2 * c + 1] += p.y;
    }
}
__device__ __forceinline__ void add4(float* acc, float2 q) {
    union { float2 f; __half2 h[2]; } u; u.f = q;
    float2 p0 = __half22float2(u.h[0]);
    float2 p1 = __half22float2(u.h[1]);
    acc[0] += p0.x; acc[1] += p0.y; acc[2] += p1.x; acc[3] += p1.y;
}

// ================================================================ layer 1 aggregation (PURE gather)
// Wave-per-node, upfront-batched float2 gathers, butterfly reduce; writes a1 row
// (16 f32, 64B) from the sub==0 lanes. The 16-deep serial shfl-FMA GEMM chain
// is split out into gemm1_kernel (same fix that worked for layer 2).
__global__ __launch_bounds__(256) void agg1_kernel(const __half2* __restrict__ g1h,
                                                   const int2* __restrict__ rowinfo,
                                                   const unsigned short* __restrict__ nbr,
                                                   float* __restrict__ a1) {
    const float2* g1v = (const float2*)g1h;   // row = 4 float2
    int t    = threadIdx.x;
    int lane = t & 63;
    int w    = t >> 6;
    int f4   = lane & 3;
    int sub  = lane >> 2;          // 16 edge-slots per batch
    int v    = blockIdx.x * NPB + w;
    int2 ri  = rowinfo[v];
    int nb   = (int)nbr[ri.x + lane];
#pragma unroll 1
    for (int it = 0; it < NPB / 4; ++it) {
        int vc = v;
        int r0 = ri.x, er = ri.y;
        int nbc = nb;
        float2 sq = g1v[(vc << 2) + f4];      // self row, early
        // upfront: edges 0..31 via 2 independent loads
        int s0 = sub, s1 = 16 + sub;
        int u0 = __shfl(nbc, s0 < er ? s0 : 0, 64);
        int u1 = __shfl(nbc, s1 < er ? s1 : 0, 64);
        float2 q0 = g1v[(u0 << 2) + f4];
        float2 q1 = g1v[(u1 << 2) + f4];
        if (it < NPB / 4 - 1) ri = rowinfo[vc + 4];   // prefetch next rowinfo
        float acc[4] = {0.f, 0.f, 0.f, 0.f};
        if (s0 < er) add4(acc, q0);
        if (s1 < er) add4(acc, q1);
        // tail: er > 32 (rare)
        int j = 32;
        for (; j + 32 <= er; j += 32) {
            int a0 = __shfl(nbc, j + sub, 64);
            int a1i = __shfl(nbc, j + 16 + sub, 64);
            float2 t0 = g1v[(a0 << 2) + f4];
            float2 t1 = g1v[(a1i << 2) + f4];
            add4(acc, t0);
            add4(acc, t1);
        }
        for (; j < er && j < 64; j += 16) {
            int idx = j + sub;
            int u = __shfl(nbc, idx < er ? idx : 0, 64);
            float2 q = g1v[(u << 2) + f4];
            if (idx < er) add4(acc, q);
        }
        for (int base = 64; base < er; base += 64) {   // essentially never (deg>64)
            int nbx = (int)nbr[r0 + base + lane];
            for (int jj = 0; jj < 64 && base + jj < er; jj += 16) {
                int idx = jj + sub;
                int u = __shfl(nbx, (base + idx) < er ? idx : 0, 64);
                float2 q = g1v[(u << 2) + f4];
                if (base + idx < er) add4(acc, q);
            }
        }
        if (it < NPB / 4 - 1) nb = (int)nbr[ri.x + lane];  // prefetch next nbr chunk
#pragma unroll
        for (int i = 0; i < 4; i++) {
            acc[i] += __shfl_xor(acc[i], 4, 64);
            acc[i] += __shfl_xor(acc[i], 8, 64);
            acc[i] += __shfl_xor(acc[i], 16, 64);
            acc[i] += __shfl_xor(acc[i], 32, 64);
        }
        add4(acc, sq);
        float dv = rsqrtf((float)(er + 1));
        if (sub == 0) {
            // lane f4 holds features 4*f4 .. 4*f4+3
            float4* dp = (float4*)(a1 + ((size_t)vc << 4) + (f4 << 2));
            dp[0] = make_float4(dv * acc[0], dv * acc[1], dv * acc[2], dv * acc[3]);
        }
        v += 4;
    }
}

// ================================================================ gemm1 (LDS-blocked, K=16)
// 64 nodes/block, 16 nodes/wave. Same blocking as gemm2_fc's GEMM:
// Ws column reads reused across 16 nodes; wave-uniform b128 a-reads broadcast.
// g2h[v] = fp16( dinv[v] * tanh(a1[v] @ W1 + b1) ).
__global__ __launch_bounds__(256) void gemm1_kernel(const float* __restrict__ a1,
                                                    const int2* __restrict__ rowinfo,
                                                    const float* __restrict__ W1,
                                                    const float* __restrict__ b1,
                                                    __half* __restrict__ g2h) {
    __shared__ float Ws[F_IN * H];   // 4 KB, [k][o]
    __shared__ float As[64 * F_IN];  // 4 KB, [node][k]
    __shared__ float bs[H];
    __shared__ float degs[64];
    int t = threadIdx.x;
    for (int i = t; i < F_IN * H; i += 256) Ws[i] = W1[i];
    if (t < H) bs[t] = b1[t];
    int v0 = blockIdx.x * 64;
    if (t < 64) degs[t] = (float)(rowinfo[v0 + t].y + 1);
    {   // stage 64 a1 rows (4 KB): one float4 per thread, coalesced
        const float4* ap = (const float4*)(a1 + ((size_t)v0 << 4));
        ((float4*)As)[t] = ap[t];
    }
    __syncthreads();
    int lane = t & 63, w = t >> 6;
    float acc[16];
#pragma unroll
    for (int j = 0; j < 16; j++) acc[j] = bs[lane];
    const float* asBase = As + ((w << 4) * F_IN);
#pragma unroll
    for (int kc = 0; kc < F_IN / 4; ++kc) {
        int k0 = kc << 2;
        float w0 = Ws[(k0 + 0) * H + lane];
        float w1 = Ws[(k0 + 1) * H + lane];
        float w2 = Ws[(k0 + 2) * H + lane];
        float w3 = Ws[(k0 + 3) * H + lane];
#pragma unroll
        for (int j = 0; j < 16; ++j) {
            float4 aq = *(const float4*)(asBase + j * F_IN + k0);   // wave-uniform -> broadcast
            acc[j] += aq.x * w0 + aq.y * w1 + aq.z * w2 + aq.w * w3;
        }
    }
    int vw = v0 + (w << 4);
#pragma unroll
    for (int j = 0; j < 16; ++j) {
        float dv = rsqrtf(degs[(w << 4) + j]);
        g2h[((size_t)(vw + j) << 6) + lane] = __float2half(dv * tanhf(acc[j]));
    }
}

// ================================================================ layer 2 aggregation (PURE gather)
// Wave-per-node. Upfront-batched: 4 independent float4 loads covering edges
// 0..31 issue before any unpack -- 2x the in-flight bytes of a rolled loop.
__global__ __launch_bounds__(256) void agg2_kernel(const __half2* __restrict__ g2h,
                                                   const int2* __restrict__ rowinfo,
                                                   const unsigned short* __restrict__ nbr,
                                                   float* __restrict__ a2) {
    const float4* g2v = (const float4*)g2h;   // row = 8 float4
    int t    = threadIdx.x;
    int lane = t & 63;
    int w    = t >> 6;
    int f8   = lane & 7;
    int sub  = lane >> 3;          // 8 edge-slots per batch
    int v    = blockIdx.x * NPB + w;
    int2 ri  = rowinfo[v];
    int nb   = (int)nbr[ri.x + lane];
#pragma unroll 1
    for (int it = 0; it < NPB / 4; ++it) {
        int vc = v;
        int r0 = ri.x, er = ri.y;
        int nbc = nb;
        float4 sq = g2v[(vc << 3) + f8];      // self row, early
        // upfront: edges 0..31 via 4 independent loads
        int s0 = sub, s1 = 8 + sub, s2 = 16 + sub, s3 = 24 + sub;
        int u0 = __shfl(nbc, s0 < er ? s0 : 0, 64);
        int u1 = __shfl(nbc, s1 < er ? s1 : 0, 64);
        int u2 = __shfl(nbc, s2 < er ? s2 : 0, 64);
        int u3 = __shfl(nbc, s3 < er ? s3 : 0, 64);
        float4 q0 = g2v[(u0 << 3) + f8];
        float4 q1 = g2v[(u1 << 3) + f8];
        float4 q2 = g2v[(u2 << 3) + f8];
        float4 q3 = g2v[(u3 << 3) + f8];
        if (it < NPB / 4 - 1) ri = rowinfo[vc + 4];   // prefetch next rowinfo
        float acc[8] = {0.f, 0.f, 0.f, 0.f, 0.f, 0.f, 0.f, 0.f};
        if (s0 < er) add8(acc, q0);
        if (s1 < er) add8(acc, q1);
        if (s2 < er) add8(acc, q2);
        if (s3 < er) add8(acc, q3);
        // tail: er > 32 (rare)
        int j = 32;
        for (; j + 16 <= er && j < 64; j += 16) {
            int a0 = __shfl(nbc, j + sub, 64);
            int a1i = __shfl(nbc, j + 8 + sub, 64);
            float4 t0 = g2v[(a0 << 3) + f8];
            float4 t1 = g2v[(a1i << 3) + f8];
            add8(acc, t0);
            add8(acc, t1);
        }
        for (; j < er && j < 64; j += 8) {
            int idx = j + sub;
            int u = __shfl(nbc, idx < er ? idx : 0, 64);
            float4 q = g2v[(u << 3) + f8];
            if (idx < er) add8(acc, q);
        }
        for (int base = 64; base < er; base += 64) {   // essentially never (deg>64)
            int nbx = (int)nbr[r0 + base + lane];
            for (int jj = 0; jj < 64 && base + jj < er; jj += 8) {
                int idx = jj + sub;
                int u = __shfl(nbx, (base + idx) < er ? idx : 0, 64);
                float4 q = g2v[(u << 3) + f8];
                if (base + idx < er) add8(acc, q);
            }
        }
        if (it < NPB / 4 - 1) nb = (int)nbr[ri.x + lane];  // prefetch next nbr chunk
#pragma unroll
        for (int i = 0; i < 8; i++) {
            acc[i] += __shfl_xor(acc[i], 8, 64);
            acc[i] += __shfl_xor(acc[i], 16, 64);
            acc[i] += __shfl_xor(acc[i], 32, 64);
        }
        add8(acc, sq);
        float dv = rsqrtf((float)(er + 1));
#pragma unroll
        for (int i = 0; i < 8; i++) acc[i] *= dv;
        if (sub == 0) {
            float4* dp = (float4*)(a2 + ((size_t)vc << 6) + (f8 << 3));
            dp[0] = make_float4(acc[0], acc[1], acc[2], acc[3]);
            dp[1] = make_float4(acc[4], acc[5], acc[6], acc[7]);
        }
        v += 4;
    }
}

// ================================================================ gemm2 + fused FC head (R7 version)
// 64 nodes/block, 16 nodes/WAVE (lane = output o, acc[16] statically indexed).
// Per k-chunk of 4: 4 conflict-free b32 Ws column reads (reused across 16 nodes)
// + 16 same-address b128 broadcast a-reads (reused across 64 outputs).
// Wfc slices read per node (L2/L3-resident, verified by FETCH_SIZE ~11 MB).
__global__ __launch_bounds__(256) void gemm2_fc_kernel(const float* __restrict__ a2,
                                                       const float* __restrict__ W2,
                                                       const float* __restrict__ b2,
                                                       const float* __restrict__ Wfc,
                                                       float* __restrict__ out) {
    __shared__ float Ws[H * H];     // 16 KB, [k][o]
    __shared__ float As[64 * H];    // 16 KB, [node][k]
    __shared__ float bs[H];
    __shared__ float red[4][OUT_F];
    int t = threadIdx.x;
    for (int i = t; i < H * H; i += 256) Ws[i] = W2[i];
    if (t < H) bs[t] = b2[t];
    {   // stage 64 a2 rows: 16 KB, 4 float4 per thread, coalesced
        const float4* ap = (const float4*)(a2 + ((size_t)blockIdx.x << 12));
        float4* asp = (float4*)As;
#pragma unroll
        for (int i = 0; i < 4; i++) asp[i * 256 + t] = ap[i * 256 + t];
    }
    __syncthreads();
    int lane = t & 63, w = t >> 6;
    int v0 = blockIdx.x * 64 + (w << 4);    // first node of this wave
    int g  = blockIdx.x >> 5;               // 32 blocks per graph
    float acc[16];
#pragma unroll
    for (int j = 0; j < 16; j++) acc[j] = bs[lane];
    const float* asBase = As + ((w << 4) * H);
#pragma unroll 2
    for (int kc = 0; kc < H / 4; ++kc) {
        int k0 = kc << 2;
        float w0 = Ws[(k0 + 0) * H + lane];
        float w1 = Ws[(k0 + 1) * H + lane];
        float w2 = Ws[(k0 + 2) * H + lane];
        float w3 = Ws[(k0 + 3) * H + lane];
#pragma unroll
        for (int j = 0; j < 16; ++j) {
            float4 aq = *(const float4*)(asBase + j * H + k0);   // wave-uniform -> broadcast
            acc[j] += aq.x * w0 + aq.y * w1 + aq.z * w2 + aq.w * w3;
        }
    }
    // FC head: fold h = tanh(acc) into graph output via Wfc slice
    float pa[OUT_F];
#pragma unroll
    for (int j = 0; j < OUT_F; j++) pa[j] = 0.f;
#pragma unroll
    for (int j = 0; j < 16; ++j) {
        float hv = tanhf(acc[j]);
        int vl = (v0 + j) & (NPG - 1);
        const float4* wr = (const float4*)(Wfc + (size_t)(vl * H + lane) * OUT_F);
        float4 q0 = wr[0], q1 = wr[1], q2 = wr[2];
        pa[0]  += hv * q0.x;  pa[1]  += hv * q0.y;
        pa[2]  += hv * q0.z;  pa[3]  += hv * q0.w;
        pa[4]  += hv * q1.x;  pa[5]  += hv * q1.y;
        pa[6]  += hv * q1.z;  pa[7]  += hv * q1.w;
        pa[8]  += hv * q2.x;  pa[9]  += hv * q2.y;
        pa[10] += hv * q2.z;  pa[11] += hv * q2.w;
    }
#pragma unroll
    for (int j = 0; j < OUT_F; j++) {
        float vv = pa[j];
        vv += __shfl_xor(vv, 1, 64);  vv += __shfl_xor(vv, 2, 64);
        vv += __shfl_xor(vv, 4, 64);  vv += __shfl_xor(vv, 8, 64);
        vv += __shfl_xor(vv, 16, 64); vv += __shfl_xor(vv, 32, 64);
        pa[j] = vv;
    }
    if (lane == 0) {
#pragma unroll
        for (int j = 0; j < OUT_F; j++) red[w][j] = pa[j];
    }
    __syncthreads();
    if (t < OUT_F)
        atomicAdd(&out[g * OUT_F + t], red[0][t] + red[1][t] + red[2][t] + red[3][t]);
}

// ================================================================ launcher
extern "C" void kernel_launch(void* const* d_in, const int* in_sizes, int n_in,
                              void* d_out, int out_size, void* d_ws, size_t ws_size,
                              hipStream_t stream) {
    const float* x    = (const float*)d_in[0];
    const int*   edge = (const int*)d_in[1];
    const int*   src  = edge;
    const int*   dst  = edge + N_EDGES;
    const float* W1  = (const float*)d_in[3];
    const float* b1  = (const float*)d_in[4];
    const float* W2  = (const float*)d_in[5];
    const float* b2  = (const float*)d_in[6];
    const float* Wfc = (const float*)d_in[7];
    const float* bfc = (const float*)d_in[8];
    float* out = (float*)d_out;

    char* p = (char*)d_ws;
    auto alloc = [&](size_t n) { char* r = p; p += (n + 255) & ~(size_t)255; return r; };
    int*   gCursor    = (int*)alloc(256 * 4);
    int2*  rowinfo    = (int2*)alloc((size_t)N_NODES * 8);
    unsigned short* nbr = (unsigned short*)alloc((size_t)256 * CAP * 2 + 256); // pad: prefetch reads up to +63
    __half* g1h       = (__half*)alloc((size_t)N_NODES * F_IN * 2);
    float* a1         = (float*)alloc((size_t)N_NODES * F_IN * 4);
    __half* g2h       = (__half*)alloc((size_t)N_NODES * H * 2);
    float* a2         = (float*)alloc((size_t)N_NODES * H * 4);
    unsigned int* binned = (unsigned int*)alloc((size_t)256 * CAP * 4);

    init_kernel<<<1, 256, 0, stream>>>(gCursor, bfc, out);
    binA_kernel<<<256, 256, 0, stream>>>(src, dst, gCursor, binned);
    binB_g1_kernel<<<256, 256, 0, stream>>>(binned, gCursor, x, rowinfo, nbr,
                                            (__half2*)g1h);
    agg1_kernel<<<N_NODES / NPB, 256, 0, stream>>>((const __half2*)g1h, rowinfo, nbr, a1);
    gemm1_kernel<<<N_NODES / 64, 256, 0, stream>>>(a1, rowinfo, W1, b1, g2h);
    agg2_kernel<<<N_NODES / NPB, 256, 0, stream>>>((const __half2*)g2h, rowinfo, nbr, a2);
    gemm2_fc_kernel<<<N_NODES / 64, 256, 0, stream>>>(a2, W2, b2, Wfc, out);
}

// Round 10
// 187.772 us; speedup vs baseline: 1.1013x; 1.0040x over previous
//
#include <hip/hip_runtime.h>
#include <hip/hip_fp16.h>

#define N_NODES 65536
#define N_EDGES 1048576
#define F_IN    16
#define H       64
#define N_GRAPHS 32
#define NPG     2048
#define OUT_F   12
#define KPG     (NPG * H)   // 131072 per-graph K for FC
#define CAP     4864        // padded per-bucket capacity: mean 4096, sigma 64, +12 sigma
#define NPB     16          // nodes per block in agg kernels

// ================================================================ CSR build
// Edges pack into uint32: src (16b) | dst (16b) << 16.
// Bucket = dst>>8 (256 buckets of 256 nodes), FIXED padded regions of CAP edges.

// 1 tiny block: init cursors to padded bucket bases; bias-init out
__global__ __launch_bounds__(256) void init_kernel(int* __restrict__ gCursor,
                                                   const float* __restrict__ bfc,
                                                   float* __restrict__ out) {
    int t = threadIdx.x;
    gCursor[t] = t * CAP;
    for (int i = t; i < N_GRAPHS * OUT_F; i += 256) out[i] = bfc[i % OUT_F];
}

// 256 blocks x 4096 edges: LDS-staged bin by dst>>8, coalesced flush into bucket regions
__global__ __launch_bounds__(256) void binA_kernel(const int* __restrict__ src,
                                                   const int* __restrict__ dst,
                                                   int* __restrict__ gCursor,
                                                   unsigned int* __restrict__ binned) {
    __shared__ int hist[256];
    __shared__ int sc[256];
    __shared__ int bnd[256];
    __shared__ int lcur[256];
    __shared__ int blkBase[256];
    __shared__ unsigned int staged[4096];
    int t = threadIdx.x;
    hist[t] = 0; lcur[t] = 0;
    __syncthreads();
    int e0 = blockIdx.x * 4096;
    unsigned int rec[16];
#pragma unroll
    for (int i = 0; i < 16; i++) {
        int e = e0 + i * 256 + t;
        unsigned int s = (unsigned int)src[e];
        unsigned int d = (unsigned int)dst[e];
        rec[i] = s | (d << 16);
        atomicAdd(&hist[d >> 8], 1);
    }
    __syncthreads();
    int cnt = hist[t];
    if (cnt) blkBase[t] = atomicAdd(&gCursor[t], cnt);
    sc[t] = cnt;
    __syncthreads();
    for (int off = 1; off < 256; off <<= 1) {
        int v = (t >= off) ? sc[t - off] : 0;
        __syncthreads();
        sc[t] += v;
        __syncthreads();
    }
    bnd[t] = sc[t] - cnt;
    __syncthreads();
#pragma unroll
    for (int i = 0; i < 16; i++) {
        int b = rec[i] >> 24;
        int p = bnd[b] + atomicAdd(&lcur[b], 1);
        staged[p] = rec[i];
    }
    __syncthreads();
    // flush: bucket of staged[i] is its own top byte -- direct lookup, no search
    for (int i = t; i < 4096; i += 256) {
        unsigned int r = staged[i];
        int b = r >> 24;
        binned[blkBase[b] + (i - bnd[b])] = r;
    }
}

// block per bucket: counting sort -> nbr (ushort), rowinfo{start,cnt}; fused g1h write
__global__ __launch_bounds__(256) void binB_g1_kernel(const unsigned int* __restrict__ binned,
                                                      const int* __restrict__ gCursor,
                                                      const float* __restrict__ x,
                                                      int2* __restrict__ rowinfo,
                                                      unsigned short* __restrict__ nbr,
                                                      __half2* __restrict__ g1h) {
    __shared__ int hist[256];
    __shared__ int sc[256];
    __shared__ int off[256];
    __shared__ int cur[256];
    __shared__ unsigned short outS[8192];
    int b = blockIdx.x, t = threadIdx.x;
    int base = b * CAP;
    int cnt  = gCursor[b] - base;   // actual edges in this bucket after binA
    hist[t] = 0; cur[t] = 0;
    __syncthreads();
    for (int i = t; i < cnt; i += 256) {
        unsigned int r = binned[base + i];
        atomicAdd(&hist[(r >> 16) & 255], 1);
    }
    __syncthreads();
    int c = hist[t];
    sc[t] = c;
    __syncthreads();
    for (int o = 1; o < 256; o <<= 1) {
        int v = (t >= o) ? sc[t - o] : 0;
        __syncthreads();
        sc[t] += v;
        __syncthreads();
    }
    off[t] = sc[t] - c;
    int nd = (b << 8) + t;
    float dv = rsqrtf((float)(c + 1));
    rowinfo[nd] = make_int2(base + sc[t] - c, c);
    {
        const float4* xr = (const float4*)(x + (size_t)nd * F_IN);
        float4 x0 = xr[0], x1 = xr[1], x2 = xr[2], x3 = xr[3];
        __half2* gr = g1h + nd * 8;
        gr[0] = __floats2half2_rn(x0.x * dv, x0.y * dv);
        gr[1] = __floats2half2_rn(x0.z * dv, x0.w * dv);
        gr[2] = __floats2half2_rn(x1.x * dv, x1.y * dv);
        gr[3] = __floats2half2_rn(x1.z * dv, x1.w * dv);
        gr[4] = __floats2half2_rn(x2.x * dv, x2.y * dv);
        gr[5] = __floats2half2_rn(x2.z * dv, x2.w * dv);
        gr[6] = __floats2half2_rn(x3.x * dv, x3.y * dv);
        gr[7] = __floats2half2_rn(x3.z * dv, x3.w * dv);
    }
    __syncthreads();
    for (int i = t; i < cnt; i += 256) {
        unsigned int r = binned[base + i];
        int n = (r >> 16) & 255;
        int p = off[n] + atomicAdd(&cur[n], 1);
        outS[p] = (unsigned short)(r & 0xFFFF);
    }
    __syncthreads();
    for (int i = t; i < cnt; i += 256) nbr[base + i] = outS[i];
}

// ---------------------------------------------------------------- unpack helpers
__device__ __forceinline__ void add8(float* acc, float4 q) {
    union { float4 f; __half2 h[4]; } u; u.f = q;
#pragma unroll
    for (int c = 0; c < 4; c++) {
        float2 p = __half22float2(u.h[c]);
        acc[2 * c]     += p.x;
        acc[2 * c + 1] += p.y;
    }
}
__device__ __forceinline__ void add4(float* acc, float2 q) {
    union { float2 f; __half2 h[2]; } u; u.f = q;
    float2 p0 = __half22float2(u.h[0]);
    float2 p1 = __half22float2(u.h[1]);
    acc[0] += p0.x; acc[1] += p0.y; acc[2] += p1.x; acc[3] += p1.y;
}

// ================================================================ layer 1 aggregation (PURE gather)
// Wave-per-node. Gather loads are EXEC-MASKED (load inside the slot predicate):
// inactive sub-groups generate zero L1 transactions, cutting ~47% of gather
// traffic at mean degree 17 (vs clamp-to-row-0 unconditional loads).
__global__ __launch_bounds__(256) void agg1_kernel(const __half2* __restrict__ g1h,
                                                   const int2* __restrict__ rowinfo,
                                                   const unsigned short* __restrict__ nbr,
                                                   float* __restrict__ a1) {
    const float2* g1v = (const float2*)g1h;   // row = 4 float2
    int t    = threadIdx.x;
    int lane = t & 63;
    int w    = t >> 6;
    int f4   = lane & 3;
    int sub  = lane >> 2;          // 16 edge-slots per batch
    int v    = blockIdx.x * NPB + w;
    int2 ri  = rowinfo[v];
    int nb   = (int)nbr[ri.x + lane];
#pragma unroll 1
    for (int it = 0; it < NPB / 4; ++it) {
        int vc = v;
        int r0 = ri.x, er = ri.y;
        int nbc = nb;
        float2 sq = g1v[(vc << 2) + f4];      // self row, early
        // upfront: edges 0..31 via 2 exec-masked loads, issued before any add
        int s0 = sub, s1 = 16 + sub;
        int u0 = __shfl(nbc, s0 < er ? s0 : 0, 64);
        int u1 = __shfl(nbc, s1 < er ? s1 : 0, 64);
        float2 q0 = make_float2(0.f, 0.f), q1 = make_float2(0.f, 0.f);
        if (s0 < er) q0 = g1v[(u0 << 2) + f4];
        if (s1 < er) q1 = g1v[(u1 << 2) + f4];
        if (it < NPB / 4 - 1) ri = rowinfo[vc + 4];   // prefetch next rowinfo
        float acc[4] = {0.f, 0.f, 0.f, 0.f};
        add4(acc, q0);
        add4(acc, q1);
        // tail: er > 32 (rare)
        int j = 32;
        for (; j + 32 <= er; j += 32) {
            int a0 = __shfl(nbc, j + sub, 64);
            int a1i = __shfl(nbc, j + 16 + sub, 64);
            float2 t0 = g1v[(a0 << 2) + f4];
            float2 t1 = g1v[(a1i << 2) + f4];
            add4(acc, t0);
            add4(acc, t1);
        }
        for (; j < er && j < 64; j += 16) {
            int idx = j + sub;
            int u = __shfl(nbc, idx < er ? idx : 0, 64);
            if (idx < er) {
                float2 q = g1v[(u << 2) + f4];
                add4(acc, q);
            }
        }
        for (int base = 64; base < er; base += 64) {   // essentially never (deg>64)
            int nbx = (int)nbr[r0 + base + lane];
            for (int jj = 0; jj < 64 && base + jj < er; jj += 16) {
                int idx = jj + sub;
                int u = __shfl(nbx, (base + idx) < er ? idx : 0, 64);
                if (base + idx < er) {
                    float2 q = g1v[(u << 2) + f4];
                    add4(acc, q);
                }
            }
        }
        if (it < NPB / 4 - 1) nb = (int)nbr[ri.x + lane];  // prefetch next nbr chunk
#pragma unroll
        for (int i = 0; i < 4; i++) {
            acc[i] += __shfl_xor(acc[i], 4, 64);
            acc[i] += __shfl_xor(acc[i], 8, 64);
            acc[i] += __shfl_xor(acc[i], 16, 64);
            acc[i] += __shfl_xor(acc[i], 32, 64);
        }
        add4(acc, sq);
        float dv = rsqrtf((float)(er + 1));
        if (sub == 0) {
            // lane f4 holds features 4*f4 .. 4*f4+3
            float4* dp = (float4*)(a1 + ((size_t)vc << 4) + (f4 << 2));
            dp[0] = make_float4(dv * acc[0], dv * acc[1], dv * acc[2], dv * acc[3]);
        }
        v += 4;
    }
}

// ================================================================ gemm1 (LDS-blocked, K=16)
// 64 nodes/block, 16 nodes/wave. Ws column reads reused across 16 nodes;
// wave-uniform b128 a-reads broadcast.
// g2h[v] = fp16( dinv[v] * tanh(a1[v] @ W1 + b1) ).
__global__ __launch_bounds__(256) void gemm1_kernel(const float* __restrict__ a1,
                                                    const int2* __restrict__ rowinfo,
                                                    const float* __restrict__ W1,
                                                    const float* __restrict__ b1,
                                                    __half* __restrict__ g2h) {
    __shared__ float Ws[F_IN * H];   // 4 KB, [k][o]
    __shared__ float As[64 * F_IN];  // 4 KB, [node][k]
    __shared__ float bs[H];
    __shared__ float degs[64];
    int t = threadIdx.x;
    for (int i = t; i < F_IN * H; i += 256) Ws[i] = W1[i];
    if (t < H) bs[t] = b1[t];
    int v0 = blockIdx.x * 64;
    if (t < 64) degs[t] = (float)(rowinfo[v0 + t].y + 1);
    {   // stage 64 a1 rows (4 KB): one float4 per thread, coalesced
        const float4* ap = (const float4*)(a1 + ((size_t)v0 << 4));
        ((float4*)As)[t] = ap[t];
    }
    __syncthreads();
    int lane = t & 63, w = t >> 6;
    float acc[16];
#pragma unroll
    for (int j = 0; j < 16; j++) acc[j] = bs[lane];
    const float* asBase = As + ((w << 4) * F_IN);
#pragma unroll
    for (int kc = 0; kc < F_IN / 4; ++kc) {
        int k0 = kc << 2;
        float w0 = Ws[(k0 + 0) * H + lane];
        float w1 = Ws[(k0 + 1) * H + lane];
        float w2 = Ws[(k0 + 2) * H + lane];
        float w3 = Ws[(k0 + 3) * H + lane];
#pragma unroll
        for (int j = 0; j < 16; ++j) {
            float4 aq = *(const float4*)(asBase + j * F_IN + k0);   // wave-uniform -> broadcast
            acc[j] += aq.x * w0 + aq.y * w1 + aq.z * w2 + aq.w * w3;
        }
    }
    int vw = v0 + (w << 4);
#pragma unroll
    for (int j = 0; j < 16; ++j) {
        float dv = rsqrtf(degs[(w << 4) + j]);
        g2h[((size_t)(vw + j) << 6) + lane] = __float2half(dv * tanhf(acc[j]));
    }
}

// ================================================================ layer 2 aggregation (PURE gather)
// Wave-per-node. 4 exec-masked float4 loads covering edges 0..31 issue before
// any unpack; inactive sub-groups cost zero memory transactions.
__global__ __launch_bounds__(256) void agg2_kernel(const __half2* __restrict__ g2h,
                                                   const int2* __restrict__ rowinfo,
                                                   const unsigned short* __restrict__ nbr,
                                                   float* __restrict__ a2) {
    const float4* g2v = (const float4*)g2h;   // row = 8 float4
    int t    = threadIdx.x;
    int lane = t & 63;
    int w    = t >> 6;
    int f8   = lane & 7;
    int sub  = lane >> 3;          // 8 edge-slots per batch
    int v    = blockIdx.x * NPB + w;
    int2 ri  = rowinfo[v];
    int nb   = (int)nbr[ri.x + lane];
#pragma unroll 1
    for (int it = 0; it < NPB / 4; ++it) {
        int vc = v;
        int r0 = ri.x, er = ri.y;
        int nbc = nb;
        float4 sq = g2v[(vc << 3) + f8];      // self row, early
        // upfront: edges 0..31 via 4 exec-masked loads
        int s0 = sub, s1 = 8 + sub, s2 = 16 + sub, s3 = 24 + sub;
        int u0 = __shfl(nbc, s0 < er ? s0 : 0, 64);
        int u1 = __shfl(nbc, s1 < er ? s1 : 0, 64);
        int u2 = __shfl(nbc, s2 < er ? s2 : 0, 64);
        int u3 = __shfl(nbc, s3 < er ? s3 : 0, 64);
        float4 q0 = make_float4(0.f, 0.f, 0.f, 0.f);
        float4 q1 = q0, q2 = q0, q3 = q0;
        if (s0 < er) q0 = g2v[(u0 << 3) + f8];
        if (s1 < er) q1 = g2v[(u1 << 3) + f8];
        if (s2 < er) q2 = g2v[(u2 << 3) + f8];
        if (s3 < er) q3 = g2v[(u3 << 3) + f8];
        if (it < NPB / 4 - 1) ri = rowinfo[vc + 4];   // prefetch next rowinfo
        float acc[8] = {0.f, 0.f, 0.f, 0.f, 0.f, 0.f, 0.f, 0.f};
        add8(acc, q0);
        add8(acc, q1);
        add8(acc, q2);
        add8(acc, q3);
        // tail: er > 32 (rare)
        int j = 32;
        for (; j + 16 <= er && j < 64; j += 16) {
            int a0 = __shfl(nbc, j + sub, 64);
            int a1i = __shfl(nbc, j + 8 + sub, 64);
            float4 t0 = g2v[(a0 << 3) + f8];
            float4 t1 = g2v[(a1i << 3) + f8];
            add8(acc, t0);
            add8(acc, t1);
        }
        for (; j < er && j < 64; j += 8) {
            int idx = j + sub;
            int u = __shfl(nbc, idx < er ? idx : 0, 64);
            if (idx < er) {
                float4 q = g2v[(u << 3) + f8];
                add8(acc, q);
            }
        }
        for (int base = 64; base < er; base += 64) {   // essentially never (deg>64)
            int nbx = (int)nbr[r0 + base + lane];
            for (int jj = 0; jj < 64 && base + jj < er; jj += 8) {
                int idx = jj + sub;
                int u = __shfl(nbx, (base + idx) < er ? idx : 0, 64);
                if (base + idx < er) {
                    float4 q = g2v[(u << 3) + f8];
                    add8(acc, q);
                }
            }
        }
        if (it < NPB / 4 - 1) nb = (int)nbr[ri.x + lane];  // prefetch next nbr chunk
#pragma unroll
        for (int i = 0; i < 8; i++) {
            acc[i] += __shfl_xor(acc[i], 8, 64);
            acc[i] += __shfl_xor(acc[i], 16, 64);
            acc[i] += __shfl_xor(acc[i], 32, 64);
        }
        add8(acc, sq);
        float dv = rsqrtf((float)(er + 1));
#pragma unroll
        for (int i = 0; i < 8; i++) acc[i] *= dv;
        if (sub == 0) {
            float4* dp = (float4*)(a2 + ((size_t)vc << 6) + (f8 << 3));
            dp[0] = make_float4(acc[0], acc[1], acc[2], acc[3]);
            dp[1] = make_float4(acc[4], acc[5], acc[6], acc[7]);
        }
        v += 4;
    }
}

// ================================================================ gemm2 + fused FC head
// 64 nodes/block, 16 nodes/WAVE (lane = output o, acc[16] statically indexed).
// Per k-chunk of 4: 4 conflict-free b32 Ws column reads (reused across 16 nodes)
// + 16 same-address b128 broadcast a-reads (reused across 64 outputs).
// Wfc slices read per node (L2/L3-resident, verified by FETCH_SIZE ~11 MB).
__global__ __launch_bounds__(256) void gemm2_fc_kernel(const float* __restrict__ a2,
                                                       const float* __restrict__ W2,
                                                       const float* __restrict__ b2,
                                                       const float* __restrict__ Wfc,
                                                       float* __restrict__ out) {
    __shared__ float Ws[H * H];     // 16 KB, [k][o]
    __shared__ float As[64 * H];    // 16 KB, [node][k]
    __shared__ float bs[H];
    __shared__ float red[4][OUT_F];
    int t = threadIdx.x;
    for (int i = t; i < H * H; i += 256) Ws[i] = W2[i];
    if (t < H) bs[t] = b2[t];
    {   // stage 64 a2 rows: 16 KB, 4 float4 per thread, coalesced
        const float4* ap = (const float4*)(a2 + ((size_t)blockIdx.x << 12));
        float4* asp = (float4*)As;
#pragma unroll
        for (int i = 0; i < 4; i++) asp[i * 256 + t] = ap[i * 256 + t];
    }
    __syncthreads();
    int lane = t & 63, w = t >> 6;
    int v0 = blockIdx.x * 64 + (w << 4);    // first node of this wave
    int g  = blockIdx.x >> 5;               // 32 blocks per graph
    float acc[16];
#pragma unroll
    for (int j = 0; j < 16; j++) acc[j] = bs[lane];
    const float* asBase = As + ((w << 4) * H);
#pragma unroll 2
    for (int kc = 0; kc < H / 4; ++kc) {
        int k0 = kc << 2;
        float w0 = Ws[(k0 + 0) * H + lane];
        float w1 = Ws[(k0 + 1) * H + lane];
        float w2 = Ws[(k0 + 2) * H + lane];
        float w3 = Ws[(k0 + 3) * H + lane];
#pragma unroll
        for (int j = 0; j < 16; ++j) {
            float4 aq = *(const float4*)(asBase + j * H + k0);   // wave-uniform -> broadcast
            acc[j] += aq.x * w0 + aq.y * w1 + aq.z * w2 + aq.w * w3;
        }
    }
    // FC head: fold h = tanh(acc) into graph output via Wfc slice
    float pa[OUT_F];
#pragma unroll
    for (int j = 0; j < OUT_F; j++) pa[j] = 0.f;
#pragma unroll
    for (int j = 0; j < 16; ++j) {
        float hv = tanhf(acc[j]);
        int vl = (v0 + j) & (NPG - 1);
        const float4* wr = (const float4*)(Wfc + (size_t)(vl * H + lane) * OUT_F);
        float4 q0 = wr[0], q1 = wr[1], q2 = wr[2];
        pa[0]  += hv * q0.x;  pa[1]  += hv * q0.y;
        pa[2]  += hv * q0.z;  pa[3]  += hv * q0.w;
        pa[4]  += hv * q1.x;  pa[5]  += hv * q1.y;
        pa[6]  += hv * q1.z;  pa[7]  += hv * q1.w;
        pa[8]  += hv * q2.x;  pa[9]  += hv * q2.y;
        pa[10] += hv * q2.z;  pa[11] += hv * q2.w;
    }
#pragma unroll
    for (int j = 0; j < OUT_F; j++) {
        float vv = pa[j];
        vv += __shfl_xor(vv, 1, 64);  vv += __shfl_xor(vv, 2, 64);
        vv += __shfl_xor(vv, 4, 64);  vv += __shfl_xor(vv, 8, 64);
        vv += __shfl_xor(vv, 16, 64); vv += __shfl_xor(vv, 32, 64);
        pa[j] = vv;
    }
    if (lane == 0) {
#pragma unroll
        for (int j = 0; j < OUT_F; j++) red[w][j] = pa[j];
    }
    __syncthreads();
    if (t < OUT_F)
        atomicAdd(&out[g * OUT_F + t], red[0][t] + red[1][t] + red[2][t] + red[3][t]);
}

// ================================================================ launcher
extern "C" void kernel_launch(void* const* d_in, const int* in_sizes, int n_in,
                              void* d_out, int out_size, void* d_ws, size_t ws_size,
                              hipStream_t stream) {
    const float* x    = (const float*)d_in[0];
    const int*   edge = (const int*)d_in[1];
    const int*   src  = edge;
    const int*   dst  = edge + N_EDGES;
    const float* W1  = (const float*)d_in[3];
    const float* b1  = (const float*)d_in[4];
    const float* W2  = (const float*)d_in[5];
    const float* b2  = (const float*)d_in[6];
    const float* Wfc = (const float*)d_in[7];
    const float* bfc = (const float*)d_in[8];
    float* out = (float*)d_out;

    char* p = (char*)d_ws;
    auto alloc = [&](size_t n) { char* r = p; p += (n + 255) & ~(size_t)255; return r; };
    int*   gCursor    = (int*)alloc(256 * 4);
    int2*  rowinfo    = (int2*)alloc((size_t)N_NODES * 8);
    unsigned short* nbr = (unsigned short*)alloc((size_t)256 * CAP * 2 + 256); // pad: prefetch reads up to +63
    __half* g1h       = (__half*)alloc((size_t)N_NODES * F_IN * 2);
    float* a1         = (float*)alloc((size_t)N_NODES * F_IN * 4);
    __half* g2h       = (__half*)alloc((size_t)N_NODES * H * 2);
    float* a2         = (float*)alloc((size_t)N_NODES * H * 4);
    unsigned int* binned = (unsigned int*)alloc((size_t)256 * CAP * 4);

    init_kernel<<<1, 256, 0, stream>>>(gCursor, bfc, out);
    binA_kernel<<<256, 256, 0, stream>>>(src, dst, gCursor, binned);
    binB_g1_kernel<<<256, 256, 0, stream>>>(binned, gCursor, x, rowinfo, nbr,
                                            (__half2*)g1h);
    agg1_kernel<<<N_NODES / NPB, 256, 0, stream>>>((const __half2*)g1h, rowinfo, nbr, a1);
    gemm1_kernel<<<N_NODES / 64, 256, 0, stream>>>(a1, rowinfo, W1, b1, g2h);
    agg2_kernel<<<N_NODES / NPB, 256, 0, stream>>>((const __half2*)g2h, rowinfo, nbr, a2);
    gemm2_fc_kernel<<<N_NODES / 64, 256, 0, stream>>>(a2, W2, b2, Wfc, out);
}